// Round 9
// baseline (3170.480 us; speedup 1.0000x reference)
//
#include <hip/hip_runtime.h>

// ---------------------------------------------------------------------------
// SGCN: 2-layer GraphSAGE('gcn') + EdgeWeightNorm('right') + mean-pool + FC
// N=100k nodes, E=3.2M edges, G=64 graphs, F=64 feats, fp32 throughout.
//
// R8 -> R9: gather inner loop is at its effective random-256B ceiling
// (R6/R7/R8 all pin at 3.2 TB/s fabric / ~126us). Attack the ~350us of aux
// kernels instead:
//  * bucket-major aggregation (k_bagg): block = 128-node bucket, 32KB LDS
//    accumulator; edges streamed from bucket-grouped list; gather + LDS
//    float atomics. csr + k_csrbuild deleted (-58MB traffic, -1 kernel).
//  * fixed per-bucket regions (BCAP = mean+9sigma): binfill reserves spans
//    via atomicAdd(cursor[b]) -> k_hist + k_scan2 deleted.
//  * binfill2 keeps LDS staging + contiguous full-line flush (R7 fix).
// Pipeline: memset, binfill2, bagg, fc, bagg, fcpool, out (7 launches).
// ---------------------------------------------------------------------------

#define CH2  4096   // edges per binfill2 block
#define BK   1024   // max buckets (N <= 131072 @ NB=128)
#define NB   128    // nodes per bucket

// scan-free binfill: LDS hist -> pair-scan (local layout) -> global span
// reserve -> LDS scatter -> contiguous flush into fixed bucket regions.
__global__ __launch_bounds__(512) void k_binfill2(
        const int* __restrict__ esrc, const int* __restrict__ edst,
        const float* __restrict__ ew, int* __restrict__ cursor,
        int2* __restrict__ bsw, unsigned char* __restrict__ bdl,
        int E, int B, int BCAP) {
    __shared__ int2 stg[CH2];            // 32 KB
    __shared__ unsigned char sdl[CH2];   //  4 KB
    __shared__ int h[BK];                //  4 KB
    __shared__ int lcur[BK];             //  4 KB
    __shared__ int gb[BK];               //  4 KB
    __shared__ int sc[512];              //  2 KB
    const int tid = threadIdx.x;

    for (int i = tid; i < BK; i += 512) h[i] = 0;
    __syncthreads();
    int e0 = blockIdx.x * CH2;
    int e1 = min(E, e0 + CH2);
    for (int e = e0 + tid; e < e1; e += 512)
        atomicAdd(&h[edst[e] >> 7], 1);
    __syncthreads();
    // pair scan: thread t owns entries 2t, 2t+1
    int a0 = h[2 * tid], a1 = h[2 * tid + 1];
    int s  = a0 + a1;
    sc[tid] = s;
    __syncthreads();
    for (int off = 1; off < 512; off <<= 1) {
        int t = (tid >= off) ? sc[tid - off] : 0;
        __syncthreads();
        sc[tid] += t;
        __syncthreads();
    }
    int base = sc[tid] - s;               // exclusive over pairs
    lcur[2 * tid]     = base;
    lcur[2 * tid + 1] = base + a0;
    gb[2 * tid]     = a0 ? atomicAdd(&cursor[2 * tid],     a0) : 0;
    gb[2 * tid + 1] = a1 ? atomicAdd(&cursor[2 * tid + 1], a1) : 0;
    __syncthreads();
    // scatter into bucket-grouped staging
    for (int e = e0 + tid; e < e1; e += 512) {
        int d = edst[e];
        int b = d >> 7;
        int p = atomicAdd(&lcur[b], 1);
        stg[p] = make_int2(esrc[e], __float_as_int(ew[e]));
        sdl[p] = (unsigned char)(d & 127);
    }
    __syncthreads();
    // contiguous flush: wave w handles buckets w, w+8, ...
    const int wid = tid >> 6, lane = tid & 63;
    for (int b = wid; b < B; b += 8) {
        int len = h[b];
        if (!len) continue;
        int lb = lcur[b] - len;
        int g  = gb[b];
        int wlen = min(len, BCAP - g);
        if (wlen <= 0) continue;
        size_t gbase = (size_t)b * BCAP + g;
        for (int i = lane; i < wlen; i += 64) {
            bsw[gbase + i] = stg[lb + i];
            bdl[gbase + i] = sdl[lb + i];
        }
    }
}

// bucket-major aggregate: block = one 128-node bucket, LDS accumulator tile.
//   agg[node] = (sum_e w_e x[src_e] / sum_e w_e + x[node]) / (deg+1)
__global__ __launch_bounds__(512) void k_bagg(
        const float* __restrict__ x, const int2* __restrict__ bsw,
        const unsigned char* __restrict__ bdl, const int* __restrict__ cursor,
        float* __restrict__ agg, int N, int BCAP) {
    __shared__ float acc[NB * 64];       // 32 KB
    __shared__ float ssw[NB];
    __shared__ int   scnt[NB];
    const int tid  = threadIdx.x;
    const int lane = tid & 63;
    const int wid  = __builtin_amdgcn_readfirstlane(tid >> 6);
    const int b    = blockIdx.x;

    for (int i = tid; i < NB * 64; i += 512) acc[i] = 0.f;
    if (tid < NB) { ssw[tid] = 0.f; scnt[tid] = 0; }
    __syncthreads();

    const int cnt = min(cursor[b], BCAP);
    const int2* __restrict__ eb = bsw + (size_t)b * BCAP;
    const unsigned char* __restrict__ db = bdl + (size_t)b * BCAP;
    const int per = (cnt + 7) >> 3;      // 8 waves per block
    const int s0  = wid * per;
    const int s1  = min(cnt, s0 + per);

    int i = s0;
    for (; i + 4 <= s1; i += 4) {        // 4 independent gathers in flight
        int2 e0 = eb[i], e1 = eb[i + 1], e2 = eb[i + 2], e3 = eb[i + 3];
        int  d0 = db[i], d1 = db[i + 1], d2 = db[i + 2], d3 = db[i + 3];
        float w0 = __int_as_float(e0.y), w1 = __int_as_float(e1.y);
        float w2 = __int_as_float(e2.y), w3 = __int_as_float(e3.y);
        float v0 = x[(size_t)e0.x * 64 + lane];
        float v1 = x[(size_t)e1.x * 64 + lane];
        float v2 = x[(size_t)e2.x * 64 + lane];
        float v3 = x[(size_t)e3.x * 64 + lane];
        atomicAdd(&acc[d0 * 64 + lane], w0 * v0);
        atomicAdd(&acc[d1 * 64 + lane], w1 * v1);
        atomicAdd(&acc[d2 * 64 + lane], w2 * v2);
        atomicAdd(&acc[d3 * 64 + lane], w3 * v3);
        if (lane == 0) {
            atomicAdd(&ssw[d0], w0); atomicAdd(&ssw[d1], w1);
            atomicAdd(&ssw[d2], w2); atomicAdd(&ssw[d3], w3);
            atomicAdd(&scnt[d0], 1); atomicAdd(&scnt[d1], 1);
            atomicAdd(&scnt[d2], 1); atomicAdd(&scnt[d3], 1);
        }
    }
    for (; i < s1; ++i) {
        int2 e = eb[i]; int d = db[i];
        float w = __int_as_float(e.y);
        float v = x[(size_t)e.x * 64 + lane];
        atomicAdd(&acc[d * 64 + lane], w * v);
        if (lane == 0) { atomicAdd(&ssw[d], w); atomicAdd(&scnt[d], 1); }
    }
    __syncthreads();
    // finalize: wave handles nodes wid, wid+8, ...; coalesced 256B rows
    for (int n = wid; n < NB; n += 8) {
        int node = b * NB + n;
        if (node >= N) continue;
        float sw = ssw[n];
        int   c  = scnt[n];
        float invw = (sw > 0.f) ? 1.f / sw : 0.f;
        float invd = 1.f / ((float)c + 1.f);
        float self = x[(size_t)node * 64 + lane];
        agg[(size_t)node * 64 + lane] = (acc[n * 64 + lane] * invw + self) * invd;
    }
}

// ---- fallback kernels (R8 pipeline) ----
__global__ void k_fill_pad(const int* __restrict__ esrc, const int* __restrict__ edst,
                           const float* __restrict__ ew, int* __restrict__ fill,
                           int2* __restrict__ csr, int E, int CAP) {
    int e = blockIdx.x * blockDim.x + threadIdx.x;
    if (e < E) {
        int d = edst[e];
        int p = atomicAdd(&fill[d], 1);
        if (p < CAP)
            csr[(size_t)d * CAP + p] = make_int2(esrc[e], __float_as_int(ew[e]));
    }
}

__global__ void k_cnt(const int* __restrict__ edst, int* __restrict__ cnt, int E) {
    int e = blockIdx.x * blockDim.x + threadIdx.x;
    if (e < E) atomicAdd(&cnt[edst[e]], 1);
}

__global__ void k_off(const int* __restrict__ cnt, int* __restrict__ off,
                      int* __restrict__ fill, int* __restrict__ cursor, int N) {
    int i    = blockIdx.x * blockDim.x + threadIdx.x;
    int lane = threadIdx.x & 63;
    int c    = (i < N) ? cnt[i] : 0;
    int pref = c;
    #pragma unroll
    for (int d = 1; d < 64; d <<= 1) {
        int t = __shfl_up(pref, d);
        if (lane >= d) pref += t;
    }
    int total = __shfl(pref, 63);
    int base  = 0;
    if (lane == 63) base = atomicAdd(cursor, total);
    base = __shfl(base, 63);
    if (i < N) {
        int p = base + pref - c;
        off[i]  = p;
        fill[i] = p;
    }
}

__global__ void k_fill(const int* __restrict__ esrc, const int* __restrict__ edst,
                       const float* __restrict__ ew, int* __restrict__ fill,
                       int2* __restrict__ csr, int E) {
    int e = blockIdx.x * blockDim.x + threadIdx.x;
    if (e < E) {
        int d = edst[e];
        int p = atomicAdd(&fill[d], 1);
        csr[p] = make_int2(esrc[e], __float_as_int(ew[e]));
    }
}

// fallback agg (R8): wave = one node; lane = (slot[2], f8[32]).
__global__ __launch_bounds__(256, 4) void k_agg(
        const float* __restrict__ x, const int* __restrict__ off,
        const int* __restrict__ cnt_arr, const int2* __restrict__ csr,
        float* __restrict__ agg, int N, int CAP) {
    const int lane   = threadIdx.x & 63;
    const int slot   = lane >> 5;
    const int f8     = lane & 31;
    const int wave   = (blockIdx.x * blockDim.x + threadIdx.x) >> 6;
    const int nwaves = (gridDim.x * blockDim.x) >> 6;
    const float2* __restrict__ xv = (const float2*)x;

    int node  = wave;
    int cnt_p = 0, start_p = 0;
    if (node < N) {
        cnt_p   = cnt_arr[node];
        start_p = (CAP > 0) ? node * CAP : off[node];
        if (CAP > 0) cnt_p = min(cnt_p, CAP);
    }
    for (; node < N; node += nwaves) {
        const int cnt = cnt_p, start = start_p;
        int nn = node + nwaves;
        if (nn < N) {
            cnt_p   = cnt_arr[nn];
            start_p = (CAP > 0) ? nn * CAP : off[nn];
            if (CAP > 0) cnt_p = min(cnt_p, CAP);
        }
        int2 ee = make_int2(0, 0);
        if (lane < cnt) ee = csr[start + lane];
        float2 acc0 = {0.f, 0.f}, acc1 = {0.f, 0.f};
        float  sw = 0.0f;
        for (int bk = 0; bk < cnt; bk += 64) {
            int   s_l = ee.x;
            float w_l = __int_as_float(ee.y);
            int2 en = make_int2(0, 0);
            int  rem = cnt - bk - 64;
            if (lane < rem) en = csr[start + bk + 64 + lane];
            sw += w_l;
            #pragma unroll
            for (int half = 0; half < 2; ++half) {
                float  w[16];
                float2 v[16];
                #pragma unroll
                for (int k = 0; k < 16; ++k) {
                    int idx = half * 32 + 2 * k + slot;
                    int s   = __shfl(s_l, idx);
                    w[k]    = __shfl(w_l, idx);
                    v[k]    = xv[(size_t)s * 32 + f8];
                }
                #pragma unroll
                for (int k = 0; k < 16; k += 2) {
                    acc0.x = fmaf(w[k],   v[k].x,   acc0.x);
                    acc0.y = fmaf(w[k],   v[k].y,   acc0.y);
                    acc1.x = fmaf(w[k+1], v[k+1].x, acc1.x);
                    acc1.y = fmaf(w[k+1], v[k+1].y, acc1.y);
                }
            }
            ee = en;
        }
        acc0.x += acc1.x; acc0.y += acc1.y;
        acc0.x += __shfl_xor(acc0.x, 32);
        acc0.y += __shfl_xor(acc0.y, 32);
        #pragma unroll
        for (int mask = 1; mask <= 32; mask <<= 1) sw += __shfl_xor(sw, mask);
        float invw = (sw > 0.0f) ? (1.0f / sw) : 0.0f;
        float invd = 1.0f / ((float)cnt + 1.0f);
        if (lane < 32) {
            float2 xs = xv[(size_t)node * 32 + f8];
            float2 hn;
            hn.x = (acc0.x * invw + xs.x) * invd;
            hn.y = (acc0.y * invw + xs.y) * invd;
            ((float2*)agg)[(size_t)node * 32 + f8] = hn;
        }
    }
}

// k_fc: h = [relu](agg @ W + b); out may alias agg (in-place, row-local).
__global__ __launch_bounds__(256) void k_fc(
        const float* __restrict__ agg, const float* __restrict__ W,
        const float* __restrict__ b, float* __restrict__ out, int N, int do_relu) {
    __shared__ float sW[64 * 64];
    __shared__ float sb[64];
    for (int i = threadIdx.x; i < 64 * 64; i += blockDim.x) sW[i] = W[i];
    if (threadIdx.x < 64) sb[threadIdx.x] = b[threadIdx.x];
    __syncthreads();
    const int lane   = threadIdx.x & 63;
    const int wave   = (blockIdx.x * blockDim.x + threadIdx.x) >> 6;
    const int nwaves = (gridDim.x * blockDim.x) >> 6;
    for (int node = wave; node < N; node += nwaves) {
        float hn = agg[(size_t)node * 64 + lane];
        float o  = sb[lane];
        #pragma unroll
        for (int f = 0; f < 64; ++f) {
            float hf = __shfl(hn, f);
            o = fmaf(hf, sW[f * 64 + lane], o);
        }
        if (do_relu) o = fmaxf(o, 0.0f);
        out[(size_t)node * 64 + lane] = o;
    }
}

// fc (with relu) + mean-pool fused; gid sorted -> run-length flush.
__global__ __launch_bounds__(256) void k_fcpool(
        const float* __restrict__ agg, const float* __restrict__ W,
        const float* __restrict__ b, const int* __restrict__ gid,
        float* __restrict__ hg, float* __restrict__ cntg, int N) {
    __shared__ float sW[64 * 64];
    __shared__ float sb[64];
    for (int i = threadIdx.x; i < 64 * 64; i += blockDim.x) sW[i] = W[i];
    if (threadIdx.x < 64) sb[threadIdx.x] = b[threadIdx.x];
    __syncthreads();
    const int lane   = threadIdx.x & 63;
    const int wave   = (blockIdx.x * blockDim.x + threadIdx.x) >> 6;
    const int nwaves = (gridDim.x * blockDim.x) >> 6;
    const int per    = (N + nwaves - 1) / nwaves;
    const int start  = wave * per;
    const int end    = min(N, start + per);
    if (start >= N) return;

    int   curg = -1;
    float acc  = 0.0f;
    int   c    = 0;
    for (int node = start; node < end; ++node) {
        float hn = agg[(size_t)node * 64 + lane];
        float o  = sb[lane];
        #pragma unroll
        for (int f = 0; f < 64; ++f) {
            float hf = __shfl(hn, f);
            o = fmaf(hf, sW[f * 64 + lane], o);
        }
        o = fmaxf(o, 0.0f);
        int g = gid[node];
        if (g != curg) {
            if (c > 0) {
                atomicAdd(&hg[curg * 64 + lane], acc);
                if (lane == 0) atomicAdd(&cntg[curg], (float)c);
            }
            curg = g; acc = 0.0f; c = 0;
        }
        acc += o;
        ++c;
    }
    if (c > 0) {
        atomicAdd(&hg[curg * 64 + lane], acc);
        if (lane == 0) atomicAdd(&cntg[curg], (float)c);
    }
}

__global__ void k_out(const float* __restrict__ hg, const float* __restrict__ cntg,
                      const float* __restrict__ Wc, const float* __restrict__ bc,
                      float* __restrict__ out, int G) {
    int t = blockIdx.x * blockDim.x + threadIdx.x;
    if (t >= G * 2) return;
    int g = t >> 1, c = t & 1;
    float ct = fmaxf(cntg[g], 1.0f);
    float o  = bc[c];
    for (int f = 0; f < 64; ++f)
        o += (hg[g * 64 + f] / ct) * Wc[f * 2 + c];
    out[t] = o;
}

extern "C" void kernel_launch(void* const* d_in, const int* in_sizes, int n_in,
                              void* d_out, int out_size, void* d_ws, size_t ws_size,
                              hipStream_t stream) {
    const float* in_feat = (const float*)d_in[0];
    const float* ew      = (const float*)d_in[1];
    const float* W1      = (const float*)d_in[2];
    const float* b1      = (const float*)d_in[3];
    const float* W2      = (const float*)d_in[4];
    const float* b2      = (const float*)d_in[5];
    const float* Wc      = (const float*)d_in[6];
    const float* bc      = (const float*)d_in[7];
    const int*   esrc    = (const int*)d_in[8];
    const int*   edst    = (const int*)d_in[9];
    const int*   gid     = (const int*)d_in[10];

    const int E = in_sizes[1];
    const int N = in_sizes[10];
    const int G = out_size / 2;
    float* outp = (float*)d_out;

    auto alignup = [](size_t x) { return (x + 15) & ~(size_t)15; };
    char* base = (char*)d_ws;
    const int FC_BLK = 1024;

    // ---- main path: bucket-major (R9) ----
    const int B     = (N + NB - 1) / NB;                   // 128-node buckets
    const int EperB = (E + B - 1) / B;
    const int BCAP  = ((EperB + (EperB >> 3) + 64) + 7) & ~7;   // mean + >9 sigma
    const int NBLK2 = (E + CH2 - 1) / CH2;

    size_t zhdr  = ((size_t)G * 64 + G + BK) * 4;          // hg, cntg, cursor
    size_t o_bsw = alignup(zhdr);
    size_t o_bdl = o_bsw + alignup((size_t)B * BCAP * 8);
    size_t o_t1  = o_bdl + alignup((size_t)B * BCAP);
    size_t o_t2  = o_t1 + alignup((size_t)N * 64 * 4);
    size_t needB = o_t2 + (size_t)N * 64 * 4;

    if (ws_size >= needB && B <= BK) {
        float* hg     = (float*)base;
        float* cntg   = hg + (size_t)G * 64;
        int*   cursor = (int*)(cntg + G);
        int2*  bsw    = (int2*)(base + o_bsw);
        unsigned char* bdl = (unsigned char*)(base + o_bdl);
        float* t1     = (float*)(base + o_t1);
        float* t2     = (float*)(base + o_t2);

        hipMemsetAsync(d_ws, 0, zhdr, stream);   // hg, cntg, cursor
        k_binfill2<<<NBLK2, 512, 0, stream>>>(esrc, edst, ew, cursor, bsw, bdl, E, B, BCAP);
        k_bagg  <<<B, 512, 0, stream>>>(in_feat, bsw, bdl, cursor, t1, N, BCAP);
        k_fc    <<<FC_BLK, 256, 0, stream>>>(t1, W1, b1, t1, N, 1);
        k_bagg  <<<B, 512, 0, stream>>>(t1, bsw, bdl, cursor, t2, N, BCAP);
        k_fcpool<<<FC_BLK, 256, 0, stream>>>(t2, W2, b2, gid, hg, cntg, N);
        k_out   <<<1, 128, 0, stream>>>(hg, cntg, Wc, bc, outp, G);
        return;
    }

    // ---- fallback 1: one-pass padded scatter + R8 k_agg ----
    const int CAP = 96;
    const int AGG_BLK = 2048;
    size_t hdr    = ((size_t)G * 64 + G + 1 + N) * 4;
    size_t needB2 = alignup(hdr) + alignup((size_t)N * CAP * 8)
                  + alignup((size_t)N * 64 * 4) * 2;
    if (ws_size >= needB2) {
        size_t o = 0;
        float* hg     = (float*)(base + o);
        float* cntg   = hg + (size_t)G * 64;
        int*   fill   = (int*)(cntg + G) + 1;
        o += alignup(hdr);
        int2*  csr = (int2*)(base + o);  o += alignup((size_t)N * CAP * 8);
        float* t1  = (float*)(base + o); o += alignup((size_t)N * 64 * 4);
        float* t2  = (float*)(base + o);

        hipMemsetAsync(d_ws, 0, hdr, stream);
        k_fill_pad<<<(E + 255) / 256, 256, 0, stream>>>(esrc, edst, ew, fill, csr, E, CAP);
        k_agg   <<<AGG_BLK, 256, 0, stream>>>(in_feat, (const int*)nullptr, fill, csr, t1, N, CAP);
        k_fc    <<<FC_BLK, 256, 0, stream>>>(t1, W1, b1, t1, N, 1);
        k_agg   <<<AGG_BLK, 256, 0, stream>>>(t1, (const int*)nullptr, fill, csr, t2, N, CAP);
        k_fcpool<<<FC_BLK, 256, 0, stream>>>(t2, W2, b2, gid, hg, cntg, N);
        k_out   <<<1, 128, 0, stream>>>(hg, cntg, Wc, bc, outp, G);
        return;
    }

    // ---- fallback 2: 3-pass compact CSR ----
    {
        size_t o = 0;
        float* hg     = (float*)(base + o);
        float* cntg   = hg + (size_t)G * 64;
        int*   cursor = (int*)(cntg + G);
        int*   cnt    = cursor + 1;
        o += alignup(hdr);
        int*   off  = (int*)(base + o);  o += alignup((size_t)N * 4);
        int*   fill = (int*)(base + o);  o += alignup((size_t)N * 4);
        int2*  csr  = (int2*)(base + o); o += alignup((size_t)E * 8);
        float* t1   = (float*)(base + o); o += alignup((size_t)N * 64 * 4);
        float* t2   = (float*)(base + o);

        hipMemsetAsync(d_ws, 0, hdr, stream);
        k_cnt <<<(E + 255) / 256, 256, 0, stream>>>(edst, cnt, E);
        k_off <<<(N + 255) / 256, 256, 0, stream>>>(cnt, off, fill, cursor, N);
        k_fill<<<(E + 255) / 256, 256, 0, stream>>>(esrc, edst, ew, fill, csr, E);
        k_agg   <<<AGG_BLK, 256, 0, stream>>>(in_feat, off, cnt, csr, t1, N, 0);
        k_fc    <<<FC_BLK, 256, 0, stream>>>(t1, W1, b1, t1, N, 1);
        k_agg   <<<AGG_BLK, 256, 0, stream>>>(t1, off, cnt, csr, t2, N, 0);
        k_fcpool<<<FC_BLK, 256, 0, stream>>>(t2, W2, b2, gid, hg, cntg, N);
        k_out   <<<1, 128, 0, stream>>>(hg, cntg, Wc, bc, outp, G);
    }
}

// Round 10
// 636.145 us; speedup vs baseline: 4.9839x; 4.9839x over previous
//
#include <hip/hip_runtime.h>

// ---------------------------------------------------------------------------
// SGCN: 2-layer GraphSAGE('gcn') + EdgeWeightNorm('right') + mean-pool + FC
// N=100k nodes, E=3.2M edges, G=64 graphs, F=64 feats, fp32 throughout.
//
// R9 -> R10: k_bagg (LDS fp32 atomics per edge-lane) was 11x slower -- LDS
// atomic serialization. REVERTED to the R8 gather structure (k_agg at its
// ~3.2TB/s random-256B ceiling) and instead cut the aux chain:
//  * fixed bucket regions (BCAP=mean+16sigma): hist+scan2 deleted; binfill2
//    (R9's, correct) reserves spans via atomicAdd(cursor[b]).
//  * k_csrsort replaces k_csrbuild: block = 128-node bucket, counting-sort
//    ~4096 edges in LDS (count -> scan -> scatter), flush node-major segment
//    CONTIGUOUSLY into bucket-padded csr; off/fill from LDS prefix. No
//    scattered global stores remain anywhere.
// Pipeline: memset, binfill2, csrsort, agg, fc, agg, fcpool, out.
// ---------------------------------------------------------------------------

#define CH2  4096   // edges per binfill2 block
#define BK   1024   // max buckets
#define NB   128    // nodes per bucket
#define CAPB 5120   // bucket capacity (mean 4096 + 16 sigma)

// scan-free binfill: LDS hist -> pair-scan (local layout) -> global span
// reserve -> LDS scatter -> contiguous flush into fixed bucket regions.
__global__ __launch_bounds__(512) void k_binfill2(
        const int* __restrict__ esrc, const int* __restrict__ edst,
        const float* __restrict__ ew, int* __restrict__ cursor,
        int2* __restrict__ bsw, unsigned char* __restrict__ bdl,
        int E, int B) {
    __shared__ int2 stg[CH2];            // 32 KB
    __shared__ unsigned char sdl[CH2];   //  4 KB
    __shared__ int h[BK];                //  4 KB
    __shared__ int lcur[BK];             //  4 KB
    __shared__ int gb[BK];               //  4 KB
    __shared__ int sc[512];              //  2 KB
    const int tid = threadIdx.x;

    for (int i = tid; i < BK; i += 512) h[i] = 0;
    __syncthreads();
    int e0 = blockIdx.x * CH2;
    int e1 = min(E, e0 + CH2);
    for (int e = e0 + tid; e < e1; e += 512)
        atomicAdd(&h[edst[e] >> 7], 1);
    __syncthreads();
    // pair scan: thread t owns entries 2t, 2t+1
    int a0 = h[2 * tid], a1 = h[2 * tid + 1];
    int s  = a0 + a1;
    sc[tid] = s;
    __syncthreads();
    for (int off = 1; off < 512; off <<= 1) {
        int t = (tid >= off) ? sc[tid - off] : 0;
        __syncthreads();
        sc[tid] += t;
        __syncthreads();
    }
    int base = sc[tid] - s;               // exclusive over pairs
    lcur[2 * tid]     = base;
    lcur[2 * tid + 1] = base + a0;
    gb[2 * tid]     = a0 ? atomicAdd(&cursor[2 * tid],     a0) : 0;
    gb[2 * tid + 1] = a1 ? atomicAdd(&cursor[2 * tid + 1], a1) : 0;
    __syncthreads();
    // scatter into bucket-grouped staging
    for (int e = e0 + tid; e < e1; e += 512) {
        int d = edst[e];
        int b = d >> 7;
        int p = atomicAdd(&lcur[b], 1);
        stg[p] = make_int2(esrc[e], __float_as_int(ew[e]));
        sdl[p] = (unsigned char)(d & 127);
    }
    __syncthreads();
    // contiguous flush: wave w handles buckets w, w+8, ...
    const int wid = tid >> 6, lane = tid & 63;
    for (int b = wid; b < B; b += 8) {
        int len = h[b];
        if (!len) continue;
        int lb = lcur[b] - len;
        int g  = gb[b];
        int wlen = min(len, CAPB - g);
        if (wlen <= 0) continue;
        size_t gbase = (size_t)b * CAPB + g;
        for (int i = lane; i < wlen; i += 64) {
            bsw[gbase + i] = stg[lb + i];
            bdl[gbase + i] = sdl[lb + i];
        }
    }
}

// counting-sort a bucket's edges in LDS; flush node-major segment contiguously.
__global__ __launch_bounds__(512) void k_csrsort(
        const int2* __restrict__ bsw, const unsigned char* __restrict__ bdl,
        const int* __restrict__ cursor, int2* __restrict__ csr,
        int* __restrict__ off, int* __restrict__ fill, int N) {
    __shared__ int2 se[CAPB];            // 40 KB
    __shared__ int cur[NB];
    __shared__ int pfx[NB];
    const int b = blockIdx.x, tid = threadIdx.x;
    if (tid < NB) cur[tid] = 0;
    __syncthreads();
    const int cnt = min(cursor[b], CAPB);
    const unsigned char* __restrict__ db = bdl + (size_t)b * CAPB;
    const int2* __restrict__ eb = bsw + (size_t)b * CAPB;
    for (int i = tid; i < cnt; i += 512)
        atomicAdd(&cur[db[i]], 1);        // pass1: counts (1B coalesced reads)
    __syncthreads();
    if (tid < NB) pfx[tid] = cur[tid];
    __syncthreads();
    for (int o = 1; o < NB; o <<= 1) {    // Hillis-Steele over 128
        int t = 0;
        if (tid < NB && tid >= o) t = pfx[tid - o];
        __syncthreads();
        if (tid < NB) pfx[tid] += t;
        __syncthreads();
    }
    if (tid < NB) {
        int excl = pfx[tid] - cur[tid];
        int node = b * NB + tid;
        if (node < N) { off[node] = b * CAPB + excl; fill[node] = cur[tid]; }
        cur[tid] = excl;                  // reuse as scatter cursor
    }
    __syncthreads();
    for (int i = tid; i < cnt; i += 512) {
        int p = atomicAdd(&cur[db[i]], 1);
        se[p] = eb[i];                    // pass2: LDS scatter
    }
    __syncthreads();
    int2* __restrict__ cb = csr + (size_t)b * CAPB;
    for (int i = tid; i < cnt; i += 512)
        cb[i] = se[i];                    // contiguous full-line flush
}

// ---- fallback kernels ----
__global__ void k_fill_pad(const int* __restrict__ esrc, const int* __restrict__ edst,
                           const float* __restrict__ ew, int* __restrict__ fill,
                           int2* __restrict__ csr, int E, int CAP) {
    int e = blockIdx.x * blockDim.x + threadIdx.x;
    if (e < E) {
        int d = edst[e];
        int p = atomicAdd(&fill[d], 1);
        if (p < CAP)
            csr[(size_t)d * CAP + p] = make_int2(esrc[e], __float_as_int(ew[e]));
    }
}

__global__ void k_cnt(const int* __restrict__ edst, int* __restrict__ cnt, int E) {
    int e = blockIdx.x * blockDim.x + threadIdx.x;
    if (e < E) atomicAdd(&cnt[edst[e]], 1);
}

__global__ void k_off(const int* __restrict__ cnt, int* __restrict__ off,
                      int* __restrict__ fill, int* __restrict__ cursor, int N) {
    int i    = blockIdx.x * blockDim.x + threadIdx.x;
    int lane = threadIdx.x & 63;
    int c    = (i < N) ? cnt[i] : 0;
    int pref = c;
    #pragma unroll
    for (int d = 1; d < 64; d <<= 1) {
        int t = __shfl_up(pref, d);
        if (lane >= d) pref += t;
    }
    int total = __shfl(pref, 63);
    int base  = 0;
    if (lane == 63) base = atomicAdd(cursor, total);
    base = __shfl(base, 63);
    if (i < N) {
        int p = base + pref - c;
        off[i]  = p;
        fill[i] = p;
    }
}

__global__ void k_fill(const int* __restrict__ esrc, const int* __restrict__ edst,
                       const float* __restrict__ ew, int* __restrict__ fill,
                       int2* __restrict__ csr, int E) {
    int e = blockIdx.x * blockDim.x + threadIdx.x;
    if (e < E) {
        int d = edst[e];
        int p = atomicAdd(&fill[d], 1);
        csr[p] = make_int2(esrc[e], __float_as_int(ew[e]));
    }
}

// gather-aggregate (R8): wave = one node; lane = (slot[2], f8[32]).
//   agg[node] = (sum_e w_e x[src_e] / sum_e w_e + x[node]) / (deg+1)
__global__ __launch_bounds__(256, 4) void k_agg(
        const float* __restrict__ x, const int* __restrict__ off,
        const int* __restrict__ cnt_arr, const int2* __restrict__ csr,
        float* __restrict__ agg, int N, int CAP) {
    const int lane   = threadIdx.x & 63;
    const int slot   = lane >> 5;
    const int f8     = lane & 31;
    const int wave   = (blockIdx.x * blockDim.x + threadIdx.x) >> 6;
    const int nwaves = (gridDim.x * blockDim.x) >> 6;
    const float2* __restrict__ xv = (const float2*)x;

    int node  = wave;
    int cnt_p = 0, start_p = 0;
    if (node < N) {
        cnt_p   = cnt_arr[node];
        start_p = (CAP > 0) ? node * CAP : off[node];
        if (CAP > 0) cnt_p = min(cnt_p, CAP);
    }
    for (; node < N; node += nwaves) {
        const int cnt = cnt_p, start = start_p;
        int nn = node + nwaves;
        if (nn < N) {
            cnt_p   = cnt_arr[nn];
            start_p = (CAP > 0) ? nn * CAP : off[nn];
            if (CAP > 0) cnt_p = min(cnt_p, CAP);
        }
        int2 ee = make_int2(0, 0);
        if (lane < cnt) ee = csr[start + lane];
        float2 acc0 = {0.f, 0.f}, acc1 = {0.f, 0.f};
        float  sw = 0.0f;
        for (int bk = 0; bk < cnt; bk += 64) {
            int   s_l = ee.x;
            float w_l = __int_as_float(ee.y);
            int2 en = make_int2(0, 0);
            int  rem = cnt - bk - 64;
            if (lane < rem) en = csr[start + bk + 64 + lane];
            sw += w_l;
            #pragma unroll
            for (int half = 0; half < 2; ++half) {
                float  w[16];
                float2 v[16];
                #pragma unroll
                for (int k = 0; k < 16; ++k) {
                    int idx = half * 32 + 2 * k + slot;
                    int s   = __shfl(s_l, idx);
                    w[k]    = __shfl(w_l, idx);
                    v[k]    = xv[(size_t)s * 32 + f8];
                }
                #pragma unroll
                for (int k = 0; k < 16; k += 2) {
                    acc0.x = fmaf(w[k],   v[k].x,   acc0.x);
                    acc0.y = fmaf(w[k],   v[k].y,   acc0.y);
                    acc1.x = fmaf(w[k+1], v[k+1].x, acc1.x);
                    acc1.y = fmaf(w[k+1], v[k+1].y, acc1.y);
                }
            }
            ee = en;
        }
        acc0.x += acc1.x; acc0.y += acc1.y;
        acc0.x += __shfl_xor(acc0.x, 32);
        acc0.y += __shfl_xor(acc0.y, 32);
        #pragma unroll
        for (int mask = 1; mask <= 32; mask <<= 1) sw += __shfl_xor(sw, mask);
        float invw = (sw > 0.0f) ? (1.0f / sw) : 0.0f;
        float invd = 1.0f / ((float)cnt + 1.0f);
        if (lane < 32) {
            float2 xs = xv[(size_t)node * 32 + f8];
            float2 hn;
            hn.x = (acc0.x * invw + xs.x) * invd;
            hn.y = (acc0.y * invw + xs.y) * invd;
            ((float2*)agg)[(size_t)node * 32 + f8] = hn;
        }
    }
}

// k_fc: h = [relu](agg @ W + b); out may alias agg (in-place, row-local).
__global__ __launch_bounds__(256) void k_fc(
        const float* __restrict__ agg, const float* __restrict__ W,
        const float* __restrict__ b, float* __restrict__ out, int N, int do_relu) {
    __shared__ float sW[64 * 64];
    __shared__ float sb[64];
    for (int i = threadIdx.x; i < 64 * 64; i += blockDim.x) sW[i] = W[i];
    if (threadIdx.x < 64) sb[threadIdx.x] = b[threadIdx.x];
    __syncthreads();
    const int lane   = threadIdx.x & 63;
    const int wave   = (blockIdx.x * blockDim.x + threadIdx.x) >> 6;
    const int nwaves = (gridDim.x * blockDim.x) >> 6;
    for (int node = wave; node < N; node += nwaves) {
        float hn = agg[(size_t)node * 64 + lane];
        float o  = sb[lane];
        #pragma unroll
        for (int f = 0; f < 64; ++f) {
            float hf = __shfl(hn, f);
            o = fmaf(hf, sW[f * 64 + lane], o);
        }
        if (do_relu) o = fmaxf(o, 0.0f);
        out[(size_t)node * 64 + lane] = o;
    }
}

// fc (with relu) + mean-pool fused; gid sorted -> run-length flush.
__global__ __launch_bounds__(256) void k_fcpool(
        const float* __restrict__ agg, const float* __restrict__ W,
        const float* __restrict__ b, const int* __restrict__ gid,
        float* __restrict__ hg, float* __restrict__ cntg, int N) {
    __shared__ float sW[64 * 64];
    __shared__ float sb[64];
    for (int i = threadIdx.x; i < 64 * 64; i += blockDim.x) sW[i] = W[i];
    if (threadIdx.x < 64) sb[threadIdx.x] = b[threadIdx.x];
    __syncthreads();
    const int lane   = threadIdx.x & 63;
    const int wave   = (blockIdx.x * blockDim.x + threadIdx.x) >> 6;
    const int nwaves = (gridDim.x * blockDim.x) >> 6;
    const int per    = (N + nwaves - 1) / nwaves;
    const int start  = wave * per;
    const int end    = min(N, start + per);
    if (start >= N) return;

    int   curg = -1;
    float acc  = 0.0f;
    int   c    = 0;
    for (int node = start; node < end; ++node) {
        float hn = agg[(size_t)node * 64 + lane];
        float o  = sb[lane];
        #pragma unroll
        for (int f = 0; f < 64; ++f) {
            float hf = __shfl(hn, f);
            o = fmaf(hf, sW[f * 64 + lane], o);
        }
        o = fmaxf(o, 0.0f);
        int g = gid[node];
        if (g != curg) {
            if (c > 0) {
                atomicAdd(&hg[curg * 64 + lane], acc);
                if (lane == 0) atomicAdd(&cntg[curg], (float)c);
            }
            curg = g; acc = 0.0f; c = 0;
        }
        acc += o;
        ++c;
    }
    if (c > 0) {
        atomicAdd(&hg[curg * 64 + lane], acc);
        if (lane == 0) atomicAdd(&cntg[curg], (float)c);
    }
}

__global__ void k_out(const float* __restrict__ hg, const float* __restrict__ cntg,
                      const float* __restrict__ Wc, const float* __restrict__ bc,
                      float* __restrict__ out, int G) {
    int t = blockIdx.x * blockDim.x + threadIdx.x;
    if (t >= G * 2) return;
    int g = t >> 1, c = t & 1;
    float ct = fmaxf(cntg[g], 1.0f);
    float o  = bc[c];
    for (int f = 0; f < 64; ++f)
        o += (hg[g * 64 + f] / ct) * Wc[f * 2 + c];
    out[t] = o;
}

extern "C" void kernel_launch(void* const* d_in, const int* in_sizes, int n_in,
                              void* d_out, int out_size, void* d_ws, size_t ws_size,
                              hipStream_t stream) {
    const float* in_feat = (const float*)d_in[0];
    const float* ew      = (const float*)d_in[1];
    const float* W1      = (const float*)d_in[2];
    const float* b1      = (const float*)d_in[3];
    const float* W2      = (const float*)d_in[4];
    const float* b2      = (const float*)d_in[5];
    const float* Wc      = (const float*)d_in[6];
    const float* bc      = (const float*)d_in[7];
    const int*   esrc    = (const int*)d_in[8];
    const int*   edst    = (const int*)d_in[9];
    const int*   gid     = (const int*)d_in[10];

    const int E = in_sizes[1];
    const int N = in_sizes[10];
    const int G = out_size / 2;
    float* outp = (float*)d_out;

    auto alignup = [](size_t x) { return (x + 15) & ~(size_t)15; };
    char* base = (char*)d_ws;
    const int FC_BLK = 1024, AGG_BLK = 2048;

    // ---- main path: bucketed sort-free chain (R10) ----
    const int B     = (N + NB - 1) / NB;               // 128-node buckets
    const int NBLK2 = (E + CH2 - 1) / CH2;

    size_t zhdr  = ((size_t)G * 64 + G + BK) * 4;      // hg, cntg, cursor
    size_t o_off = alignup(zhdr);
    size_t o_fil = o_off + alignup((size_t)N * 4);
    size_t o_bsw = o_fil + alignup((size_t)N * 4);
    size_t o_bdl = o_bsw + alignup((size_t)B * CAPB * 8);
    size_t o_csr = o_bdl + alignup((size_t)B * CAPB);
    size_t o_t1  = o_csr + alignup((size_t)B * CAPB * 8);
    size_t o_t2  = o_t1 + alignup((size_t)N * 64 * 4);
    size_t needB = o_t2 + (size_t)N * 64 * 4;

    // sanity: avg edges/bucket must sit well under CAPB
    bool cap_ok = ((size_t)E / B) + 512 < CAPB;

    if (ws_size >= needB && B <= BK && cap_ok) {
        float* hg     = (float*)base;
        float* cntg   = hg + (size_t)G * 64;
        int*   cursor = (int*)(cntg + G);
        int*   off    = (int*)(base + o_off);
        int*   fill   = (int*)(base + o_fil);
        int2*  bsw    = (int2*)(base + o_bsw);
        unsigned char* bdl = (unsigned char*)(base + o_bdl);
        int2*  csr    = (int2*)(base + o_csr);
        float* t1     = (float*)(base + o_t1);
        float* t2     = (float*)(base + o_t2);

        hipMemsetAsync(d_ws, 0, zhdr, stream);   // hg, cntg, cursor
        k_binfill2<<<NBLK2, 512, 0, stream>>>(esrc, edst, ew, cursor, bsw, bdl, E, B);
        k_csrsort <<<B, 512, 0, stream>>>(bsw, bdl, cursor, csr, off, fill, N);
        k_agg   <<<AGG_BLK, 256, 0, stream>>>(in_feat, off, fill, csr, t1, N, 0);
        k_fc    <<<FC_BLK, 256, 0, stream>>>(t1, W1, b1, t1, N, 1);
        k_agg   <<<AGG_BLK, 256, 0, stream>>>(t1, off, fill, csr, t2, N, 0);
        k_fcpool<<<FC_BLK, 256, 0, stream>>>(t2, W2, b2, gid, hg, cntg, N);
        k_out   <<<1, 128, 0, stream>>>(hg, cntg, Wc, bc, outp, G);
        return;
    }

    // ---- fallback 1: one-pass padded scatter + R8 k_agg ----
    const int CAP = 96;
    size_t hdr    = ((size_t)G * 64 + G + 1 + N) * 4;
    size_t needB2 = alignup(hdr) + alignup((size_t)N * CAP * 8)
                  + alignup((size_t)N * 64 * 4) * 2;
    if (ws_size >= needB2) {
        size_t o = 0;
        float* hg     = (float*)(base + o);
        float* cntg   = hg + (size_t)G * 64;
        int*   fill   = (int*)(cntg + G) + 1;
        o += alignup(hdr);
        int2*  csr = (int2*)(base + o);  o += alignup((size_t)N * CAP * 8);
        float* t1  = (float*)(base + o); o += alignup((size_t)N * 64 * 4);
        float* t2  = (float*)(base + o);

        hipMemsetAsync(d_ws, 0, hdr, stream);
        k_fill_pad<<<(E + 255) / 256, 256, 0, stream>>>(esrc, edst, ew, fill, csr, E, CAP);
        k_agg   <<<AGG_BLK, 256, 0, stream>>>(in_feat, (const int*)nullptr, fill, csr, t1, N, CAP);
        k_fc    <<<FC_BLK, 256, 0, stream>>>(t1, W1, b1, t1, N, 1);
        k_agg   <<<AGG_BLK, 256, 0, stream>>>(t1, (const int*)nullptr, fill, csr, t2, N, CAP);
        k_fcpool<<<FC_BLK, 256, 0, stream>>>(t2, W2, b2, gid, hg, cntg, N);
        k_out   <<<1, 128, 0, stream>>>(hg, cntg, Wc, bc, outp, G);
        return;
    }

    // ---- fallback 2: 3-pass compact CSR ----
    {
        size_t o = 0;
        float* hg     = (float*)(base + o);
        float* cntg   = hg + (size_t)G * 64;
        int*   cursor = (int*)(cntg + G);
        int*   cnt    = cursor + 1;
        o += alignup(hdr);
        int*   off  = (int*)(base + o);  o += alignup((size_t)N * 4);
        int*   fill = (int*)(base + o);  o += alignup((size_t)N * 4);
        int2*  csr  = (int2*)(base + o); o += alignup((size_t)E * 8);
        float* t1   = (float*)(base + o); o += alignup((size_t)N * 64 * 4);
        float* t2   = (float*)(base + o);

        hipMemsetAsync(d_ws, 0, hdr, stream);
        k_cnt <<<(E + 255) / 256, 256, 0, stream>>>(edst, cnt, E);
        k_off <<<(N + 255) / 256, 256, 0, stream>>>(cnt, off, fill, cursor, N);
        k_fill<<<(E + 255) / 256, 256, 0, stream>>>(esrc, edst, ew, fill, csr, E);
        k_agg   <<<AGG_BLK, 256, 0, stream>>>(in_feat, off, cnt, csr, t1, N, 0);
        k_fc    <<<FC_BLK, 256, 0, stream>>>(t1, W1, b1, t1, N, 1);
        k_agg   <<<AGG_BLK, 256, 0, stream>>>(t1, off, cnt, csr, t2, N, 0);
        k_fcpool<<<FC_BLK, 256, 0, stream>>>(t2, W2, b2, gid, hg, cntg, N);
        k_out   <<<1, 128, 0, stream>>>(hg, cntg, Wc, bc, outp, G);
    }
}

// Round 11
// 526.043 us; speedup vs baseline: 6.0270x; 1.2093x over previous
//
#include <hip/hip_runtime.h>

// ---------------------------------------------------------------------------
// SGCN: 2-layer GraphSAGE('gcn') + EdgeWeightNorm('right') + mean-pool + FC
// N=100k nodes, E=3.2M edges, G=64 graphs, F=64 feats, fp32 throughout.
//
// R10 -> R11:
//  * k_fc/k_fcpool inner loop had 64 ds_read_b32 per node (~370cyc/node,
//    ~60us each). Now: per-lane W COLUMN in 64 VGPRs (coalesced row loads,
//    once), inner = readlane(SGPR path, no LDS) + fma, 4 accumulators.
//  * dl packed into bsw.x (dl<<18|src): bdl/sdl arrays deleted.
//  * agg/binfill2/csrsort structure unchanged (isolate the FC variable).
// Pipeline: memset, binfill2, csrsort, agg, fc, agg, fcpool, out.
// ---------------------------------------------------------------------------

#define CH2  4096   // edges per binfill2 block
#define BK   1024   // max buckets
#define NB   128    // nodes per bucket
#define CAPB 5120   // bucket capacity (mean 4096 + 16 sigma)
#define SRCMASK ((1 << 18) - 1)

__device__ __forceinline__ float readlane_f(float v, int l) {
    return __int_as_float(__builtin_amdgcn_readlane(__float_as_int(v), l));
}

// scan-free binfill: LDS hist -> pair-scan -> global span reserve ->
// LDS scatter (dl packed in .x) -> contiguous flush into bucket regions.
__global__ __launch_bounds__(512) void k_binfill2(
        const int* __restrict__ esrc, const int* __restrict__ edst,
        const float* __restrict__ ew, int* __restrict__ cursor,
        int2* __restrict__ bsw, int E, int B) {
    __shared__ int2 stg[CH2];            // 32 KB
    __shared__ int h[BK];                //  4 KB
    __shared__ int lcur[BK];             //  4 KB
    __shared__ int gb[BK];               //  4 KB
    __shared__ int sc[512];              //  2 KB
    const int tid = threadIdx.x;

    for (int i = tid; i < BK; i += 512) h[i] = 0;
    __syncthreads();
    int e0 = blockIdx.x * CH2;
    int e1 = min(E, e0 + CH2);
    for (int e = e0 + tid; e < e1; e += 512)
        atomicAdd(&h[edst[e] >> 7], 1);
    __syncthreads();
    // pair scan: thread t owns entries 2t, 2t+1
    int a0 = h[2 * tid], a1 = h[2 * tid + 1];
    int s  = a0 + a1;
    sc[tid] = s;
    __syncthreads();
    for (int off = 1; off < 512; off <<= 1) {
        int t = (tid >= off) ? sc[tid - off] : 0;
        __syncthreads();
        sc[tid] += t;
        __syncthreads();
    }
    int base = sc[tid] - s;               // exclusive over pairs
    lcur[2 * tid]     = base;
    lcur[2 * tid + 1] = base + a0;
    gb[2 * tid]     = a0 ? atomicAdd(&cursor[2 * tid],     a0) : 0;
    gb[2 * tid + 1] = a1 ? atomicAdd(&cursor[2 * tid + 1], a1) : 0;
    __syncthreads();
    // scatter into bucket-grouped staging; dl packed into .x bits 18..24
    for (int e = e0 + tid; e < e1; e += 512) {
        int d = edst[e];
        int b = d >> 7;
        int p = atomicAdd(&lcur[b], 1);
        stg[p] = make_int2(((d & 127) << 18) | esrc[e], __float_as_int(ew[e]));
    }
    __syncthreads();
    // contiguous flush: wave w handles buckets w, w+8, ...
    const int wid = tid >> 6, lane = tid & 63;
    for (int b = wid; b < B; b += 8) {
        int len = h[b];
        if (!len) continue;
        int lb = lcur[b] - len;
        int g  = gb[b];
        int wlen = min(len, CAPB - g);
        if (wlen <= 0) continue;
        size_t gbase = (size_t)b * CAPB + g;
        for (int i = lane; i < wlen; i += 64)
            bsw[gbase + i] = stg[lb + i];
    }
}

// counting-sort a bucket's edges in LDS; flush node-major (dl stripped).
__global__ __launch_bounds__(512) void k_csrsort(
        const int2* __restrict__ bsw, const int* __restrict__ cursor,
        int2* __restrict__ csr, int* __restrict__ off, int* __restrict__ fill,
        int N) {
    __shared__ int2 se[CAPB];            // 40 KB
    __shared__ int cur[NB];
    __shared__ int pfx[NB];
    const int b = blockIdx.x, tid = threadIdx.x;
    if (tid < NB) cur[tid] = 0;
    __syncthreads();
    const int cnt = min(cursor[b], CAPB);
    const int2* __restrict__ eb = bsw + (size_t)b * CAPB;
    for (int i = tid; i < cnt; i += 512)
        atomicAdd(&cur[eb[i].x >> 18], 1);   // pass1: counts
    __syncthreads();
    if (tid < NB) pfx[tid] = cur[tid];
    __syncthreads();
    for (int o = 1; o < NB; o <<= 1) {       // Hillis-Steele over 128
        int t = 0;
        if (tid < NB && tid >= o) t = pfx[tid - o];
        __syncthreads();
        if (tid < NB) pfx[tid] += t;
        __syncthreads();
    }
    if (tid < NB) {
        int excl = pfx[tid] - cur[tid];
        int node = b * NB + tid;
        if (node < N) { off[node] = b * CAPB + excl; fill[node] = cur[tid]; }
        cur[tid] = excl;                     // reuse as scatter cursor
    }
    __syncthreads();
    for (int i = tid; i < cnt; i += 512) {
        int2 e = eb[i];
        int p = atomicAdd(&cur[e.x >> 18], 1);
        se[p] = e;                           // pass2: LDS scatter
    }
    __syncthreads();
    int2* __restrict__ cb = csr + (size_t)b * CAPB;
    for (int i = tid; i < cnt; i += 512) {
        int2 e = se[i];
        cb[i] = make_int2(e.x & SRCMASK, e.y);   // contiguous full-line flush
    }
}

// ---- fallback kernels ----
__global__ void k_fill_pad(const int* __restrict__ esrc, const int* __restrict__ edst,
                           const float* __restrict__ ew, int* __restrict__ fill,
                           int2* __restrict__ csr, int E, int CAP) {
    int e = blockIdx.x * blockDim.x + threadIdx.x;
    if (e < E) {
        int d = edst[e];
        int p = atomicAdd(&fill[d], 1);
        if (p < CAP)
            csr[(size_t)d * CAP + p] = make_int2(esrc[e], __float_as_int(ew[e]));
    }
}

__global__ void k_cnt(const int* __restrict__ edst, int* __restrict__ cnt, int E) {
    int e = blockIdx.x * blockDim.x + threadIdx.x;
    if (e < E) atomicAdd(&cnt[edst[e]], 1);
}

__global__ void k_off(const int* __restrict__ cnt, int* __restrict__ off,
                      int* __restrict__ fill, int* __restrict__ cursor, int N) {
    int i    = blockIdx.x * blockDim.x + threadIdx.x;
    int lane = threadIdx.x & 63;
    int c    = (i < N) ? cnt[i] : 0;
    int pref = c;
    #pragma unroll
    for (int d = 1; d < 64; d <<= 1) {
        int t = __shfl_up(pref, d);
        if (lane >= d) pref += t;
    }
    int total = __shfl(pref, 63);
    int base  = 0;
    if (lane == 63) base = atomicAdd(cursor, total);
    base = __shfl(base, 63);
    if (i < N) {
        int p = base + pref - c;
        off[i]  = p;
        fill[i] = p;
    }
}

__global__ void k_fill(const int* __restrict__ esrc, const int* __restrict__ edst,
                       const float* __restrict__ ew, int* __restrict__ fill,
                       int2* __restrict__ csr, int E) {
    int e = blockIdx.x * blockDim.x + threadIdx.x;
    if (e < E) {
        int d = edst[e];
        int p = atomicAdd(&fill[d], 1);
        csr[p] = make_int2(esrc[e], __float_as_int(ew[e]));
    }
}

// gather-aggregate (R8): wave = one node; lane = (slot[2], f8[32]).
//   agg[node] = (sum_e w_e x[src_e] / sum_e w_e + x[node]) / (deg+1)
__global__ __launch_bounds__(256, 4) void k_agg(
        const float* __restrict__ x, const int* __restrict__ off,
        const int* __restrict__ cnt_arr, const int2* __restrict__ csr,
        float* __restrict__ agg, int N, int CAP) {
    const int lane   = threadIdx.x & 63;
    const int slot   = lane >> 5;
    const int f8     = lane & 31;
    const int wave   = (blockIdx.x * blockDim.x + threadIdx.x) >> 6;
    const int nwaves = (gridDim.x * blockDim.x) >> 6;
    const float2* __restrict__ xv = (const float2*)x;

    int node  = wave;
    int cnt_p = 0, start_p = 0;
    if (node < N) {
        cnt_p   = cnt_arr[node];
        start_p = (CAP > 0) ? node * CAP : off[node];
        if (CAP > 0) cnt_p = min(cnt_p, CAP);
    }
    for (; node < N; node += nwaves) {
        const int cnt = cnt_p, start = start_p;
        int nn = node + nwaves;
        if (nn < N) {
            cnt_p   = cnt_arr[nn];
            start_p = (CAP > 0) ? nn * CAP : off[nn];
            if (CAP > 0) cnt_p = min(cnt_p, CAP);
        }
        int2 ee = make_int2(0, 0);
        if (lane < cnt) ee = csr[start + lane];
        float2 acc0 = {0.f, 0.f}, acc1 = {0.f, 0.f};
        float  sw = 0.0f;
        for (int bk = 0; bk < cnt; bk += 64) {
            int   s_l = ee.x;
            float w_l = __int_as_float(ee.y);
            int2 en = make_int2(0, 0);
            int  rem = cnt - bk - 64;
            if (lane < rem) en = csr[start + bk + 64 + lane];
            sw += w_l;
            #pragma unroll
            for (int half = 0; half < 2; ++half) {
                float  w[16];
                float2 v[16];
                #pragma unroll
                for (int k = 0; k < 16; ++k) {
                    int idx = half * 32 + 2 * k + slot;
                    int s   = __shfl(s_l, idx);
                    w[k]    = __shfl(w_l, idx);
                    v[k]    = xv[(size_t)s * 32 + f8];
                }
                #pragma unroll
                for (int k = 0; k < 16; k += 2) {
                    acc0.x = fmaf(w[k],   v[k].x,   acc0.x);
                    acc0.y = fmaf(w[k],   v[k].y,   acc0.y);
                    acc1.x = fmaf(w[k+1], v[k+1].x, acc1.x);
                    acc1.y = fmaf(w[k+1], v[k+1].y, acc1.y);
                }
            }
            ee = en;
        }
        acc0.x += acc1.x; acc0.y += acc1.y;
        acc0.x += __shfl_xor(acc0.x, 32);
        acc0.y += __shfl_xor(acc0.y, 32);
        #pragma unroll
        for (int mask = 1; mask <= 32; mask <<= 1) sw += __shfl_xor(sw, mask);
        float invw = (sw > 0.0f) ? (1.0f / sw) : 0.0f;
        float invd = 1.0f / ((float)cnt + 1.0f);
        if (lane < 32) {
            float2 xs = xv[(size_t)node * 32 + f8];
            float2 hn;
            hn.x = (acc0.x * invw + xs.x) * invd;
            hn.y = (acc0.y * invw + xs.y) * invd;
            ((float2*)agg)[(size_t)node * 32 + f8] = hn;
        }
    }
}

// k_fc: h = [relu](agg @ W + b). Per-lane W column in regs; readlane inner.
__global__ __launch_bounds__(256) void k_fc(
        const float* __restrict__ agg, const float* __restrict__ W,
        const float* __restrict__ b, float* __restrict__ out, int N, int do_relu) {
    const int lane   = threadIdx.x & 63;
    const int wave   = (blockIdx.x * blockDim.x + threadIdx.x) >> 6;
    const int nwaves = (gridDim.x * blockDim.x) >> 6;
    float wc[64];
    #pragma unroll
    for (int f = 0; f < 64; ++f) wc[f] = W[f * 64 + lane];   // coalesced rows
    const float bias = b[lane];
    for (int node = wave; node < N; node += nwaves) {
        float hn = agg[(size_t)node * 64 + lane];
        float o0 = bias, o1 = 0.f, o2 = 0.f, o3 = 0.f;
        #pragma unroll
        for (int f = 0; f < 64; f += 4) {
            o0 = fmaf(readlane_f(hn, f),     wc[f],     o0);
            o1 = fmaf(readlane_f(hn, f + 1), wc[f + 1], o1);
            o2 = fmaf(readlane_f(hn, f + 2), wc[f + 2], o2);
            o3 = fmaf(readlane_f(hn, f + 3), wc[f + 3], o3);
        }
        float o = (o0 + o1) + (o2 + o3);
        if (do_relu) o = fmaxf(o, 0.0f);
        out[(size_t)node * 64 + lane] = o;
    }
}

// fc (with relu) + mean-pool fused; gid sorted -> run-length flush.
__global__ __launch_bounds__(256) void k_fcpool(
        const float* __restrict__ agg, const float* __restrict__ W,
        const float* __restrict__ b, const int* __restrict__ gid,
        float* __restrict__ hg, float* __restrict__ cntg, int N) {
    const int lane   = threadIdx.x & 63;
    const int wave   = (blockIdx.x * blockDim.x + threadIdx.x) >> 6;
    const int nwaves = (gridDim.x * blockDim.x) >> 6;
    float wc[64];
    #pragma unroll
    for (int f = 0; f < 64; ++f) wc[f] = W[f * 64 + lane];
    const float bias = b[lane];
    const int per   = (N + nwaves - 1) / nwaves;
    const int start = wave * per;
    const int end   = min(N, start + per);
    if (start >= N) return;

    int   curg = -1;
    float acc  = 0.0f;
    int   c    = 0;
    for (int node = start; node < end; ++node) {
        float hn = agg[(size_t)node * 64 + lane];
        float o0 = bias, o1 = 0.f, o2 = 0.f, o3 = 0.f;
        #pragma unroll
        for (int f = 0; f < 64; f += 4) {
            o0 = fmaf(readlane_f(hn, f),     wc[f],     o0);
            o1 = fmaf(readlane_f(hn, f + 1), wc[f + 1], o1);
            o2 = fmaf(readlane_f(hn, f + 2), wc[f + 2], o2);
            o3 = fmaf(readlane_f(hn, f + 3), wc[f + 3], o3);
        }
        float o = fmaxf((o0 + o1) + (o2 + o3), 0.0f);
        int g = gid[node];
        if (g != curg) {
            if (c > 0) {
                atomicAdd(&hg[curg * 64 + lane], acc);
                if (lane == 0) atomicAdd(&cntg[curg], (float)c);
            }
            curg = g; acc = 0.0f; c = 0;
        }
        acc += o;
        ++c;
    }
    if (c > 0) {
        atomicAdd(&hg[curg * 64 + lane], acc);
        if (lane == 0) atomicAdd(&cntg[curg], (float)c);
    }
}

__global__ void k_out(const float* __restrict__ hg, const float* __restrict__ cntg,
                      const float* __restrict__ Wc, const float* __restrict__ bc,
                      float* __restrict__ out, int G) {
    int t = blockIdx.x * blockDim.x + threadIdx.x;
    if (t >= G * 2) return;
    int g = t >> 1, c = t & 1;
    float ct = fmaxf(cntg[g], 1.0f);
    float o  = bc[c];
    for (int f = 0; f < 64; ++f)
        o += (hg[g * 64 + f] / ct) * Wc[f * 2 + c];
    out[t] = o;
}

extern "C" void kernel_launch(void* const* d_in, const int* in_sizes, int n_in,
                              void* d_out, int out_size, void* d_ws, size_t ws_size,
                              hipStream_t stream) {
    const float* in_feat = (const float*)d_in[0];
    const float* ew      = (const float*)d_in[1];
    const float* W1      = (const float*)d_in[2];
    const float* b1      = (const float*)d_in[3];
    const float* W2      = (const float*)d_in[4];
    const float* b2      = (const float*)d_in[5];
    const float* Wc      = (const float*)d_in[6];
    const float* bc      = (const float*)d_in[7];
    const int*   esrc    = (const int*)d_in[8];
    const int*   edst    = (const int*)d_in[9];
    const int*   gid     = (const int*)d_in[10];

    const int E = in_sizes[1];
    const int N = in_sizes[10];
    const int G = out_size / 2;
    float* outp = (float*)d_out;

    auto alignup = [](size_t x) { return (x + 15) & ~(size_t)15; };
    char* base = (char*)d_ws;
    const int FC_BLK = 1024, AGG_BLK = 2048;

    // ---- main path: bucketed sort chain (R11) ----
    const int B     = (N + NB - 1) / NB;               // 128-node buckets
    const int NBLK2 = (E + CH2 - 1) / CH2;

    size_t zhdr  = ((size_t)G * 64 + G + BK) * 4;      // hg, cntg, cursor
    size_t o_off = alignup(zhdr);
    size_t o_fil = o_off + alignup((size_t)N * 4);
    size_t o_bsw = o_fil + alignup((size_t)N * 4);
    size_t o_csr = o_bsw + alignup((size_t)B * CAPB * 8);
    size_t o_t1  = o_csr + alignup((size_t)B * CAPB * 8);
    size_t o_t2  = o_t1 + alignup((size_t)N * 64 * 4);
    size_t needB = o_t2 + (size_t)N * 64 * 4;

    bool cap_ok = ((size_t)E / B) + 512 < CAPB && N <= (1 << 18);

    if (ws_size >= needB && B <= BK && cap_ok) {
        float* hg     = (float*)base;
        float* cntg   = hg + (size_t)G * 64;
        int*   cursor = (int*)(cntg + G);
        int*   off    = (int*)(base + o_off);
        int*   fill   = (int*)(base + o_fil);
        int2*  bsw    = (int2*)(base + o_bsw);
        int2*  csr    = (int2*)(base + o_csr);
        float* t1     = (float*)(base + o_t1);
        float* t2     = (float*)(base + o_t2);

        hipMemsetAsync(d_ws, 0, zhdr, stream);   // hg, cntg, cursor
        k_binfill2<<<NBLK2, 512, 0, stream>>>(esrc, edst, ew, cursor, bsw, E, B);
        k_csrsort <<<B, 512, 0, stream>>>(bsw, cursor, csr, off, fill, N);
        k_agg   <<<AGG_BLK, 256, 0, stream>>>(in_feat, off, fill, csr, t1, N, 0);
        k_fc    <<<FC_BLK, 256, 0, stream>>>(t1, W1, b1, t1, N, 1);
        k_agg   <<<AGG_BLK, 256, 0, stream>>>(t1, off, fill, csr, t2, N, 0);
        k_fcpool<<<FC_BLK, 256, 0, stream>>>(t2, W2, b2, gid, hg, cntg, N);
        k_out   <<<1, 128, 0, stream>>>(hg, cntg, Wc, bc, outp, G);
        return;
    }

    // ---- fallback 1: one-pass padded scatter + k_agg ----
    const int CAP = 96;
    size_t hdr    = ((size_t)G * 64 + G + 1 + N) * 4;
    size_t needB2 = alignup(hdr) + alignup((size_t)N * CAP * 8)
                  + alignup((size_t)N * 64 * 4) * 2;
    if (ws_size >= needB2) {
        size_t o = 0;
        float* hg     = (float*)(base + o);
        float* cntg   = hg + (size_t)G * 64;
        int*   fill   = (int*)(cntg + G) + 1;
        o += alignup(hdr);
        int2*  csr = (int2*)(base + o);  o += alignup((size_t)N * CAP * 8);
        float* t1  = (float*)(base + o); o += alignup((size_t)N * 64 * 4);
        float* t2  = (float*)(base + o);

        hipMemsetAsync(d_ws, 0, hdr, stream);
        k_fill_pad<<<(E + 255) / 256, 256, 0, stream>>>(esrc, edst, ew, fill, csr, E, CAP);
        k_agg   <<<AGG_BLK, 256, 0, stream>>>(in_feat, (const int*)nullptr, fill, csr, t1, N, CAP);
        k_fc    <<<FC_BLK, 256, 0, stream>>>(t1, W1, b1, t1, N, 1);
        k_agg   <<<AGG_BLK, 256, 0, stream>>>(t1, (const int*)nullptr, fill, csr, t2, N, CAP);
        k_fcpool<<<FC_BLK, 256, 0, stream>>>(t2, W2, b2, gid, hg, cntg, N);
        k_out   <<<1, 128, 0, stream>>>(hg, cntg, Wc, bc, outp, G);
        return;
    }

    // ---- fallback 2: 3-pass compact CSR ----
    {
        size_t o = 0;
        float* hg     = (float*)(base + o);
        float* cntg   = hg + (size_t)G * 64;
        int*   cursor = (int*)(cntg + G);
        int*   cnt    = cursor + 1;
        o += alignup(hdr);
        int*   off  = (int*)(base + o);  o += alignup((size_t)N * 4);
        int*   fill = (int*)(base + o);  o += alignup((size_t)N * 4);
        int2*  csr  = (int2*)(base + o); o += alignup((size_t)E * 8);
        float* t1   = (float*)(base + o); o += alignup((size_t)N * 64 * 4);
        float* t2   = (float*)(base + o);

        hipMemsetAsync(d_ws, 0, hdr, stream);
        k_cnt <<<(E + 255) / 256, 256, 0, stream>>>(edst, cnt, E);
        k_off <<<(N + 255) / 256, 256, 0, stream>>>(cnt, off, fill, cursor, N);
        k_fill<<<(E + 255) / 256, 256, 0, stream>>>(esrc, edst, ew, fill, csr, E);
        k_agg   <<<AGG_BLK, 256, 0, stream>>>(in_feat, off, cnt, csr, t1, N, 0);
        k_fc    <<<FC_BLK, 256, 0, stream>>>(t1, W1, b1, t1, N, 1);
        k_agg   <<<AGG_BLK, 256, 0, stream>>>(t1, off, cnt, csr, t2, N, 0);
        k_fcpool<<<FC_BLK, 256, 0, stream>>>(t2, W2, b2, gid, hg, cntg, N);
        k_out   <<<1, 128, 0, stream>>>(hg, cntg, Wc, bc, outp, G);
    }
}